// Round 1
// baseline (242.778 us; speedup 1.0000x reference)
//
#include <hip/hip_runtime.h>
#include <math.h>

// NetVLAD on gfx950. Sizes fixed: N=64, C=128, P=4096, K=64.
//
// v2: c-major contiguous DMA (1-KB rows) into a persistent bf16 tile,
//     tri-buffered staging with counted vmcnt; atomics replaced by
//     partial-tile stores + reduce-in-finish when ws_size permits.
#define NNIMG 64
#define CCH 128
#define KK 64
#define PP 4096
#define BSPLIT 16
#define PB 256              // pixels per block
#define NCHUNK 32           // 32 chunks of 4 C-rows
#define TILE_U32 (PB * 66)  // [256 px][66 u32], e = c>>1, u32 = bf16|bf16<<16

typedef __attribute__((ext_vector_type(8))) short short8;
typedef __attribute__((ext_vector_type(4))) float f32x4;

__device__ __forceinline__ unsigned short bf16_rtne(float f) {
  unsigned u = __float_as_uint(f);
  unsigned r = u + 0x7FFFu + ((u >> 16) & 1u);
  return (unsigned short)(r >> 16);
}
__device__ __forceinline__ float bf16_tof(unsigned short h) {
  return __uint_as_float(((unsigned)h) << 16);
}
__device__ __forceinline__ void lgkm_barrier() {
  __asm__ volatile("s_waitcnt lgkmcnt(0)\n\ts_barrier" ::: "memory");
}
__device__ __forceinline__ void load_to_lds16(const float* g, float* l) {
  __builtin_amdgcn_global_load_lds((const __attribute__((address_space(1))) void*)g,
                                   (__attribute__((address_space(3))) void*)l, 16, 0, 0);
}

// LDS (79872 B, 2 blocks/CU):
//  tile    : u32 [256 px][66]  (persistent bf16-packed x, proven bank layout) 67584 B
//  scratch : phase1 = xraw f32 [3 buf][4 c][256 px]  (tri-buffered DMA dest)  12288 B
//            phase2 = a_lds u16 [2 pair][64 k][40] (10240) + asum f32[4][64] (1024)
template <bool USE_WS>
__global__ __launch_bounds__(256, 2) void netvlad_main(
    const float* __restrict__ x, const float* __restrict__ conv_w,
    const float* __restrict__ conv_b, float* __restrict__ vout,
    float* __restrict__ aout) {
  __shared__ __align__(16) unsigned int tile[TILE_U32];
  __shared__ __align__(16) unsigned char scratch[12288];
  float* xraw = (float*)scratch;
  unsigned short* a_lds = (unsigned short*)scratch;
  float* asum_buf = (float*)(scratch + 10240);

  const int t = threadIdx.x;
  const int lane = t & 63;
  const int wv = t >> 6;  // wave 0..3
  const int m = lane & 15;
  const int q = lane >> 4;

  const int n = blockIdx.x >> 4;
  const int blk = blockIdx.x & 15;
  const float* xbase = x + (size_t)n * CCH * PP + blk * PB;

  // One DMA inst per wave per chunk: one full C-row piece, 1 KB CONTIGUOUS.
  // The 16 sibling blocks (same n) cover the whole 16-KB DRAM row concurrently.
  auto issue_dma = [&](int ch, int buf) {
    const int c = ch * 4 + wv;
    load_to_lds16(xbase + (size_t)c * PP + lane * 4, &xraw[buf * 1024 + wv * 256]);
  };

  // ---- W hi-only fragments: A[m = k-row][kdim = c], 4kt x 4cs, 64 VGPRs ----
  short8 Whi[4][4];
#pragma unroll
  for (int kt = 0; kt < 4; ++kt)
#pragma unroll
    for (int cs = 0; cs < 4; ++cs) {
      const float* wp = conv_w + (kt * 16 + m) * CCH + cs * 32 + q * 8;
      float4 wa = *(const float4*)wp;
      float4 wb = *(const float4*)(wp + 4);
      float fv[8] = {wa.x, wa.y, wa.z, wa.w, wb.x, wb.y, wb.z, wb.w};
      short8 h;
#pragma unroll
      for (int j = 0; j < 8; ++j) h[j] = (short)bf16_rtne(fv[j]);
      Whi[kt][cs] = h;
    }
  float b_regs[4][4];
#pragma unroll
  for (int kt = 0; kt < 4; ++kt)
#pragma unroll
    for (int r = 0; r < 4; ++r) b_regs[kt][r] = conv_b[kt * 16 + q * 4 + r];
  // fence: all non-DMA vmem retired so manual vmcnt counting below is exact
  __asm__ volatile("s_waitcnt vmcnt(0)" ::: "memory");

  // ---- phase 1: tri-buffered DMA + bf16 pack into persistent tile ----
  issue_dma(0, 0);
  issue_dma(1, 1);
  issue_dma(2, 2);
  const unsigned sel_hi = 0x07060302u;  // perm: hi16 of each f32 (bf16 trunc)

#pragma unroll 1
  for (int ch = 0; ch < NCHUNK; ++ch) {
    if (ch <= NCHUNK - 3)      __asm__ volatile("s_waitcnt vmcnt(2)" ::: "memory");
    else if (ch == NCHUNK - 2) __asm__ volatile("s_waitcnt vmcnt(1)" ::: "memory");
    else                       __asm__ volatile("s_waitcnt vmcnt(0)" ::: "memory");
    __builtin_amdgcn_s_barrier();  // chunk ch landed in all waves' rows
    const int buf = ch % 3;
    const float* xr = &xraw[buf * 1024];
    float x0 = xr[t];
    float x1 = xr[256 + t];
    float x2 = xr[512 + t];
    float x3 = xr[768 + t];
    uint2 w;
    w.x = __builtin_amdgcn_perm(__float_as_uint(x1), __float_as_uint(x0), sel_hi);
    w.y = __builtin_amdgcn_perm(__float_as_uint(x3), __float_as_uint(x2), sel_hi);
    *(uint2*)&tile[t * 66 + 2 * ch] = w;  // cols e = 2ch, 2ch+1
    __asm__ volatile("s_waitcnt lgkmcnt(0)" ::: "memory");
    __builtin_amdgcn_s_barrier();  // all waves done reading buf
    if (ch + 3 < NCHUNK) issue_dma(ch + 3, buf);
  }
  // tile published; xraw dead -> scratch becomes a_lds/asum_buf

  // ---- phase 2: wave-pair p handles 32-px groups {p, p+2, p+4, p+6} ----
  const int pair = wv >> 1;
  const int hw = wv & 1;  // c-half within pair
  unsigned short* amy = a_lds + pair * (KK * 40);
  const unsigned sel_g2 = (m & 1) ? 0x07060302u : 0x05040100u;

  f32x4 vacc[4][4];  // V[k: 4 kt][c: 4 ct within wave's 64-c half]
#pragma unroll
  for (int kt = 0; kt < 4; ++kt)
#pragma unroll
    for (int ct = 0; ct < 4; ++ct) vacc[kt][ct] = (f32x4){0.f, 0.f, 0.f, 0.f};
  float asum_acc[16];
#pragma unroll
  for (int i = 0; i < 16; ++i) asum_acc[i] = 0.f;

#pragma unroll 1
  for (int gi = 0; gi < 4; ++gi) {
    const int px0 = (pair + 2 * gi) * 32;
    const int prow = px0 + hw * 16 + m;

    // GEMM1: L[64 k][px=prow] = Whi . x_hi, K=128 over 4 cs
    f32x4 acc1[4];
#pragma unroll
    for (int kt = 0; kt < 4; ++kt)
      acc1[kt] = (f32x4){b_regs[kt][0], b_regs[kt][1], b_regs[kt][2], b_regs[kt][3]};
    const unsigned int* pcrow = tile + prow * 66;
#pragma unroll
    for (int cs = 0; cs < 4; ++cs) {
      uint2 u01 = *(const uint2*)&pcrow[16 * cs + 4 * q];
      uint2 u23 = *(const uint2*)&pcrow[16 * cs + 4 * q + 2];
      unsigned hs[4] = {u01.x, u01.y, u23.x, u23.y};
      short8 Bf;
      __builtin_memcpy(&Bf, hs, 16);
#pragma unroll
      for (int kt = 0; kt < 4; ++kt)
        acc1[kt] = __builtin_amdgcn_mfma_f32_16x16x32_bf16(Whi[kt][cs], Bf, acc1[kt], 0, 0, 0);
    }

    // softmax over k (register-resident; lane holds 16 of 64 k)
    float ssum = 0.f;
#pragma unroll
    for (int kt = 0; kt < 4; ++kt)
#pragma unroll
      for (int r = 0; r < 4; ++r) {
        float e = __expf(acc1[kt][r]);
        acc1[kt][r] = e;
        ssum += e;
      }
    ssum += __shfl_xor(ssum, 16, 64);
    ssum += __shfl_xor(ssum, 32, 64);
    float inv = 1.0f / ssum;
#pragma unroll
    for (int kt = 0; kt < 4; ++kt)
#pragma unroll
      for (int r = 0; r < 4; ++r) {
        float a = acc1[kt][r] * inv;
        unsigned short h = bf16_rtne(a);
        asum_acc[kt * 4 + r] += bf16_tof(h);
        amy[(kt * 16 + q * 4 + r) * 40 + hw * 16 + m] = h;
      }
    lgkm_barrier();  // a_lds published (block-wide; pairs run in lockstep)

    // GEMM2: V[k][c] += A[k][px] . x_hi^T[px][c], K=32 one shot
    short8 Af[4];
#pragma unroll
    for (int kt = 0; kt < 4; ++kt)
      Af[kt] = *(const short8*)&amy[(kt * 16 + m) * 40 + q * 8];
#pragma unroll
    for (int ct = 0; ct < 4; ++ct) {
      const int ebase = hw * 32 + ct * 8 + (m >> 1);
      unsigned g[8];
#pragma unroll
      for (int j = 0; j < 8; ++j) g[j] = tile[(px0 + q * 8 + j) * 66 + ebase];
      unsigned hs2[4];
#pragma unroll
      for (int i = 0; i < 4; ++i)
        hs2[i] = __builtin_amdgcn_perm(g[2 * i + 1], g[2 * i], sel_g2);
      short8 Bf;
      __builtin_memcpy(&Bf, hs2, 16);
#pragma unroll
      for (int kt = 0; kt < 4; ++kt)
        vacc[kt][ct] = __builtin_amdgcn_mfma_f32_16x16x32_bf16(Af[kt], Bf, vacc[kt][ct], 0, 0, 0);
    }
    lgkm_barrier();  // amy reads drained before next group's writes
  }

  // ---- epilogue: merge pair1 into pair0 via tile (dead), then output ----
  float* vscr = (float*)tile;
  if (pair == 1) {
#pragma unroll
    for (int kt = 0; kt < 4; ++kt)
#pragma unroll
      for (int ct = 0; ct < 4; ++ct)
#pragma unroll
        for (int r = 0; r < 4; ++r)
          vscr[(kt * 16 + q * 4 + r) * CCH + hw * 64 + ct * 16 + m] = vacc[kt][ct][r];
  }
#pragma unroll
  for (int i = 0; i < 16; ++i) {
    float v = asum_acc[i];
    v += __shfl_xor(v, 1, 64);
    v += __shfl_xor(v, 2, 64);
    v += __shfl_xor(v, 4, 64);
    v += __shfl_xor(v, 8, 64);
    if (m == 0) asum_buf[wv * 64 + (i >> 2) * 16 + q * 4 + (i & 3)] = v;
  }
  lgkm_barrier();
  if (pair == 0) {
    float* vrow = USE_WS ? (vout + (size_t)blockIdx.x * (KK * CCH))
                         : (vout + (size_t)n * (KK * CCH));
#pragma unroll
    for (int kt = 0; kt < 4; ++kt)
#pragma unroll
      for (int ct = 0; ct < 4; ++ct)
#pragma unroll
        for (int r = 0; r < 4; ++r) {
          const int idx = (kt * 16 + q * 4 + r) * CCH + hw * 64 + ct * 16 + m;
          const float v = vacc[kt][ct][r] + vscr[idx];
          if (USE_WS) vrow[idx] = v;
          else atomicAdd(&vrow[idx], v);
        }
  }
  if (t < KK) {
    float s = asum_buf[t] + asum_buf[64 + t] + asum_buf[128 + t] + asum_buf[192 + t];
    if (USE_WS) aout[blockIdx.x * KK + t] = s;
    else atomicAdd(&aout[n * KK + t], s);
  }
}

// Fallback finish (atomic-accumulated vg/ag), unchanged from v1.
__global__ __launch_bounds__(256) void netvlad_finish(
    const float* __restrict__ vg, const float* __restrict__ ag,
    const float* __restrict__ centroids, float* __restrict__ out) {
  const int t = threadIdx.x;
  const int w = t >> 6, ln = t & 63;
  const int idx = blockIdx.x * 4 + w;  // 0..4095
  const int n = idx >> 6, k = idx & 63;
  const int c = ln * 2;
  float2 v = *(const float2*)&vg[(size_t)(n * KK + k) * CCH + c];
  float s = ag[n * KK + k];
  float2 ce = *(const float2*)&centroids[k * CCH + c];
  float v0 = v.x - s * ce.x;
  float v1 = v.y - s * ce.y;
  float ssq = v0 * v0 + v1 * v1;
#pragma unroll
  for (int off = 32; off > 0; off >>= 1) ssq += __shfl_xor(ssq, off, 64);
  float inv = 0.125f / fmaxf(sqrtf(ssq), 1e-12f);
  float2 o;
  o.x = v0 * inv;
  o.y = v1 * inv;
  *(float2*)&out[(size_t)n * (KK * CCH) + k * CCH + c] = o;
}

// WS finish: 16-way partial reduction + centroid subtract + per-cluster L2.
__global__ __launch_bounds__(256) void netvlad_finish_ws(
    const float* __restrict__ vp, const float* __restrict__ agp,
    const float* __restrict__ centroids, float* __restrict__ out) {
  const int t = threadIdx.x;
  const int w = t >> 6, ln = t & 63;
  const int idx = blockIdx.x * 4 + w;  // 0..4095
  const int n = idx >> 6, k = idx & 63;
  const int c = ln * 2;
  float a0 = 0.f, a1 = 0.f, s = 0.f;
#pragma unroll
  for (int b = 0; b < BSPLIT; ++b) {
    const float* vr = vp + (size_t)(n * BSPLIT + b) * (KK * CCH) + k * CCH + c;
    float2 v = *(const float2*)vr;
    a0 += v.x;
    a1 += v.y;
    s += agp[(n * BSPLIT + b) * KK + k];
  }
  float2 ce = *(const float2*)&centroids[k * CCH + c];
  float v0 = a0 - s * ce.x;
  float v1 = a1 - s * ce.y;
  float ssq = v0 * v0 + v1 * v1;
#pragma unroll
  for (int off = 32; off > 0; off >>= 1) ssq += __shfl_xor(ssq, off, 64);
  float inv = 0.125f / fmaxf(sqrtf(ssq), 1e-12f);
  float2 o;
  o.x = v0 * inv;
  o.y = v1 * inv;
  *(float2*)&out[(size_t)n * (KK * CCH) + k * CCH + c] = o;
}

extern "C" void kernel_launch(void* const* d_in, const int* in_sizes, int n_in,
                              void* d_out, int out_size, void* d_ws, size_t ws_size,
                              hipStream_t stream) {
  const float* x = (const float*)d_in[0];          // (64,128,64,64)
  const float* conv_w = (const float*)d_in[1];     // (64,128)
  const float* conv_b = (const float*)d_in[2];     // (64,)
  const float* centroids = (const float*)d_in[3];  // (64,128)
  float* out = (float*)d_out;                      // (64, 8192)

  const size_t WS_NEEDED =
      ((size_t)NNIMG * BSPLIT * KK * CCH + (size_t)NNIMG * BSPLIT * KK) * sizeof(float);

  if (ws_size >= WS_NEEDED) {
    // partial-store path: no atomics, no memset
    float* vp = (float*)d_ws;                           // [1024][8192] f32
    float* agp = vp + (size_t)NNIMG * BSPLIT * KK * CCH;  // [1024][64] f32
    netvlad_main<true><<<NNIMG * BSPLIT, 256, 0, stream>>>(x, conv_w, conv_b, vp, agp);
    netvlad_finish_ws<<<NNIMG * KK / 4, 256, 0, stream>>>(vp, agp, centroids, out);
  } else {
    // atomic fallback
    float* vg = (float*)d_ws;                       // 64*64*128 f32 = 2 MiB
    float* ag = vg + (size_t)NNIMG * KK * CCH;      // 64*64 f32
    const size_t zbytes = ((size_t)NNIMG * KK * CCH + NNIMG * KK) * sizeof(float);
    hipMemsetAsync(d_ws, 0, zbytes, stream);
    netvlad_main<false><<<NNIMG * BSPLIT, 256, 0, stream>>>(x, conv_w, conv_b, vg, ag);
    netvlad_finish<<<NNIMG * KK / 4, 256, 0, stream>>>(vg, ag, centroids, out);
  }
}

// Round 2
// 217.247 us; speedup vs baseline: 1.1175x; 1.1175x over previous
//
#include <hip/hip_runtime.h>
#include <math.h>

// NetVLAD on gfx950. Sizes fixed: N=64, C=128, P=4096, K=64.
//
// v3: register staging (global->reg->pc), per-wave compiler waitcnt instead of
//     block-wide vmcnt(0) drains, double-buffered pc (2 barriers/chunk),
//     partial-tile stores + reduce-in-finish (no atomics, no memset).
#define NNIMG 64
#define CCH 128
#define KK 64
#define PP 4096
#define BSPLIT 16
#define PB 256             // pixels per block
#define PC 32              // pixels per chunk
#define NCHUNK (PB / PC)   // 8

typedef __attribute__((ext_vector_type(8))) short short8;
typedef __attribute__((ext_vector_type(4))) float f32x4;

__device__ __forceinline__ unsigned short bf16_rtne(float f) {
  unsigned u = __float_as_uint(f);
  unsigned r = u + 0x7FFFu + ((u >> 16) & 1u);
  return (unsigned short)(r >> 16);
}
__device__ __forceinline__ float bf16_tof(unsigned short h) {
  return __uint_as_float(((unsigned)h) << 16);
}
__device__ __forceinline__ void lgkm_barrier() {
  __asm__ volatile("s_waitcnt lgkmcnt(0)\n\ts_barrier" ::: "memory");
}

// LDS (22528 B):
//  pc   : u32 [2 buf][p=32][e=64, stride 66]; e=c>>1, u32 = bf16(x[2e])|bf16(x[2e+1])<<16
//         stage-write & G1-read & G2-gather all <=2-way bank aliasing       16896 B
//  a_lds: u16 [k=64][p stride 40] assignments bf16 (b128-aligned reads)      5120 B
//  asum_buf: f32 [2][64]                                                      512 B
template <bool USE_WS>
__global__ __launch_bounds__(128, 2) void netvlad_main(
    const float* __restrict__ x, const float* __restrict__ conv_w,
    const float* __restrict__ conv_b, float* __restrict__ vout,
    float* __restrict__ aout) {
  __shared__ __align__(16) unsigned int pc[2][PC * 66];
  __shared__ __align__(16) unsigned short a_lds[KK * 40];
  __shared__ float asum_buf[2 * KK];

  const int t = threadIdx.x;
  const int lane = t & 63;
  const int wv = t >> 6;      // wave 0..1
  const int m = lane & 15;
  const int q = lane >> 4;

  const int n = blockIdx.x >> 4;
  const int blk = blockIdx.x & 15;
  const float* xbase = x + (size_t)n * CCH * PP + blk * PB;

  // Staging: thread owns 4 even/odd C-row pairs x 4 px (16 B each).
  // inst j: row = wv*64 + (j>>1)*16 + (lane>>3)*2 + (j&1), px = (lane&7)*4
  const int lrow = lane >> 3;        // 0..7
  const int lpx = (lane & 7) * 4;    // 0..28
  f32x4 sreg[8];
  auto issue_loads = [&](int ch) {
#pragma unroll
    for (int j = 0; j < 8; ++j) {
      const int row = wv * 64 + (j >> 1) * 16 + lrow * 2 + (j & 1);
      sreg[j] = *(const f32x4*)(xbase + (size_t)row * PP + ch * PC + lpx);
    }
  };

  issue_loads(0);  // deepest-latency loads first

  // ---- W hi-only fragments: A[m = k-row][kdim = c], 4kt x 4cs, 64 VGPRs ----
  short8 Whi[4][4];
#pragma unroll
  for (int kt = 0; kt < 4; ++kt)
#pragma unroll
    for (int cs = 0; cs < 4; ++cs) {
      const float* wp = conv_w + (kt * 16 + m) * CCH + cs * 32 + q * 8;
      float4 wa = *(const float4*)wp;
      float4 wb = *(const float4*)(wp + 4);
      float fv[8] = {wa.x, wa.y, wa.z, wa.w, wb.x, wb.y, wb.z, wb.w};
      short8 h;
#pragma unroll
      for (int j = 0; j < 8; ++j) h[j] = (short)bf16_rtne(fv[j]);
      Whi[kt][cs] = h;
    }
  float b_regs[4][4];
#pragma unroll
  for (int kt = 0; kt < 4; ++kt)
#pragma unroll
    for (int r = 0; r < 4; ++r) b_regs[kt][r] = conv_b[kt * 16 + q * 4 + r];

  f32x4 vacc[4][4];  // V[k: 4 kt][c: 4 ct within wave's 64-c half]
#pragma unroll
  for (int kt = 0; kt < 4; ++kt)
#pragma unroll
    for (int ct = 0; ct < 4; ++ct) vacc[kt][ct] = (f32x4){0.f, 0.f, 0.f, 0.f};
  float asum_acc[16];
#pragma unroll
  for (int i = 0; i < 16; ++i) asum_acc[i] = 0.f;

  const int prow = wv * 16 + m;         // GEMM1: lane's pixel column (0..31)
  const unsigned sel_hi = 0x07060302u;  // perm: hi16 of each src (bf16 trunc)
  const unsigned sel_g2 = (m & 1) ? 0x07060302u : 0x05040100u;

#pragma unroll 1
  for (int ch = 0; ch < NCHUNK; ++ch) {
    unsigned int* pcb = pc[ch & 1];

    // ---- pack: sreg (chunk ch) -> pcb; compiler inserts the vmcnt waits ----
#pragma unroll
    for (int u = 0; u < 4; ++u) {
      const int e = wv * 32 + u * 8 + lrow;
      f32x4 ev = sreg[2 * u];
      f32x4 od = sreg[2 * u + 1];
#pragma unroll
      for (int pi = 0; pi < 4; ++pi)
        pcb[(lpx + pi) * 66 + e] =
            __builtin_amdgcn_perm(__float_as_uint(od[pi]), __float_as_uint(ev[pi]), sel_hi);
    }
    // issue next chunk's loads now: in flight across GEMM1+softmax+GEMM2
    if (ch + 1 < NCHUNK) issue_loads(ch + 1);
    lgkm_barrier();  // B1: pcb published

    // ---- GEMM1: L[64 k][p=prow] = Whi . x_hi, K=128 over 4 cs ----
    f32x4 acc1[4];
#pragma unroll
    for (int kt = 0; kt < 4; ++kt)
      acc1[kt] = (f32x4){b_regs[kt][0], b_regs[kt][1], b_regs[kt][2], b_regs[kt][3]};
    const unsigned int* pcrow = pcb + prow * 66;
#pragma unroll
    for (int cs = 0; cs < 4; ++cs) {
      uint2 u01 = *(const uint2*)&pcrow[16 * cs + 4 * q];
      uint2 u23 = *(const uint2*)&pcrow[16 * cs + 4 * q + 2];
      unsigned hs[4] = {u01.x, u01.y, u23.x, u23.y};
      short8 Bf;
      __builtin_memcpy(&Bf, hs, 16);
#pragma unroll
      for (int kt = 0; kt < 4; ++kt)
        acc1[kt] = __builtin_amdgcn_mfma_f32_16x16x32_bf16(Whi[kt][cs], Bf, acc1[kt], 0, 0, 0);
    }

    // ---- softmax over k (register-resident; lane holds 16 of 64 k) ----
    float ssum = 0.f;
#pragma unroll
    for (int kt = 0; kt < 4; ++kt)
#pragma unroll
      for (int r = 0; r < 4; ++r) {
        float e = __expf(acc1[kt][r]);
        acc1[kt][r] = e;
        ssum += e;
      }
    ssum += __shfl_xor(ssum, 16, 64);
    ssum += __shfl_xor(ssum, 32, 64);
    float inv = 1.0f / ssum;
#pragma unroll
    for (int kt = 0; kt < 4; ++kt)
#pragma unroll
      for (int r = 0; r < 4; ++r) {
        float a = acc1[kt][r] * inv;
        unsigned short h = bf16_rtne(a);
        asum_acc[kt * 4 + r] += bf16_tof(h);  // consistent with GEMM2's operand
        a_lds[(kt * 16 + q * 4 + r) * 40 + prow] = h;
      }
    lgkm_barrier();  // B2: a_lds published

    // ---- GEMM2: V[k][c] += A[k][p] . x_hi^T[p][c], K=32 one shot ----
    short8 Af[4];
#pragma unroll
    for (int kt = 0; kt < 4; ++kt)
      Af[kt] = *(const short8*)&a_lds[(kt * 16 + m) * 40 + q * 8];
#pragma unroll
    for (int ct = 0; ct < 4; ++ct) {
      const int ebase = wv * 32 + ct * 8 + (m >> 1);
      unsigned g[8];
#pragma unroll
      for (int j = 0; j < 8; ++j) g[j] = pcb[(q * 8 + j) * 66 + ebase];
      unsigned hs2[4];
#pragma unroll
      for (int i = 0; i < 4; ++i)
        hs2[i] = __builtin_amdgcn_perm(g[2 * i + 1], g[2 * i], sel_g2);
      short8 Bf;
      __builtin_memcpy(&Bf, hs2, 16);
#pragma unroll
      for (int kt = 0; kt < 4; ++kt)
        vacc[kt][ct] = __builtin_amdgcn_mfma_f32_16x16x32_bf16(Af[kt], Bf, vacc[kt][ct], 0, 0, 0);
    }
    // no trailing barrier: next pack writes pc[(ch+1)&1] (other buffer) and
    // a_lds rewrites are fenced by B1 of the next chunk.
  }

  // ---- epilogue: store partials (WS) or atomic-accumulate (fallback) ----
  float* vrow = USE_WS ? (vout + (size_t)blockIdx.x * (KK * CCH))
                       : (vout + (size_t)n * (KK * CCH));
#pragma unroll
  for (int kt = 0; kt < 4; ++kt)
#pragma unroll
    for (int ct = 0; ct < 4; ++ct)
#pragma unroll
      for (int r = 0; r < 4; ++r) {
        const int idx = (kt * 16 + q * 4 + r) * CCH + wv * 64 + ct * 16 + m;
        if (USE_WS) vrow[idx] = vacc[kt][ct][r];
        else atomicAdd(&vrow[idx], vacc[kt][ct][r]);
      }
  // asum: reduce over m-lanes, combine both waves via LDS
#pragma unroll
  for (int i = 0; i < 16; ++i) {
    float v = asum_acc[i];
    v += __shfl_xor(v, 1, 64);
    v += __shfl_xor(v, 2, 64);
    v += __shfl_xor(v, 4, 64);
    v += __shfl_xor(v, 8, 64);
    if (m == 0) asum_buf[wv * 64 + (i >> 2) * 16 + q * 4 + (i & 3)] = v;
  }
  lgkm_barrier();
  if (t < KK) {
    float s = asum_buf[t] + asum_buf[KK + t];
    if (USE_WS) aout[blockIdx.x * KK + t] = s;
    else atomicAdd(&aout[n * KK + t], s);
  }
}

// Fallback finish (atomic-accumulated vg/ag).
__global__ __launch_bounds__(256) void netvlad_finish(
    const float* __restrict__ vg, const float* __restrict__ ag,
    const float* __restrict__ centroids, float* __restrict__ out) {
  const int t = threadIdx.x;
  const int w = t >> 6, ln = t & 63;
  const int idx = blockIdx.x * 4 + w;  // 0..4095
  const int n = idx >> 6, k = idx & 63;
  const int c = ln * 2;
  float2 v = *(const float2*)&vg[(size_t)(n * KK + k) * CCH + c];
  float s = ag[n * KK + k];
  float2 ce = *(const float2*)&centroids[k * CCH + c];
  float v0 = v.x - s * ce.x;
  float v1 = v.y - s * ce.y;
  float ssq = v0 * v0 + v1 * v1;
#pragma unroll
  for (int off = 32; off > 0; off >>= 1) ssq += __shfl_xor(ssq, off, 64);
  float inv = 0.125f / fmaxf(sqrtf(ssq), 1e-12f);
  float2 o;
  o.x = v0 * inv;
  o.y = v1 * inv;
  *(float2*)&out[(size_t)n * (KK * CCH) + k * CCH + c] = o;
}

// WS finish: 16-way partial reduction + centroid subtract + per-cluster L2.
__global__ __launch_bounds__(256) void netvlad_finish_ws(
    const float* __restrict__ vp, const float* __restrict__ agp,
    const float* __restrict__ centroids, float* __restrict__ out) {
  const int t = threadIdx.x;
  const int w = t >> 6, ln = t & 63;
  const int idx = blockIdx.x * 4 + w;  // 0..4095
  const int n = idx >> 6, k = idx & 63;
  const int c = ln * 2;
  float a0 = 0.f, a1 = 0.f, s = 0.f;
#pragma unroll
  for (int b = 0; b < BSPLIT; ++b) {
    const float* vr = vp + (size_t)(n * BSPLIT + b) * (KK * CCH) + k * CCH + c;
    float2 v = *(const float2*)vr;
    a0 += v.x;
    a1 += v.y;
    s += agp[(n * BSPLIT + b) * KK + k];
  }
  float2 ce = *(const float2*)&centroids[k * CCH + c];
  float v0 = a0 - s * ce.x;
  float v1 = a1 - s * ce.y;
  float ssq = v0 * v0 + v1 * v1;
#pragma unroll
  for (int off = 32; off > 0; off >>= 1) ssq += __shfl_xor(ssq, off, 64);
  float inv = 0.125f / fmaxf(sqrtf(ssq), 1e-12f);
  float2 o;
  o.x = v0 * inv;
  o.y = v1 * inv;
  *(float2*)&out[(size_t)n * (KK * CCH) + k * CCH + c] = o;
}

extern "C" void kernel_launch(void* const* d_in, const int* in_sizes, int n_in,
                              void* d_out, int out_size, void* d_ws, size_t ws_size,
                              hipStream_t stream) {
  const float* x = (const float*)d_in[0];          // (64,128,64,64)
  const float* conv_w = (const float*)d_in[1];     // (64,128)
  const float* conv_b = (const float*)d_in[2];     // (64,)
  const float* centroids = (const float*)d_in[3];  // (64,128)
  float* out = (float*)d_out;                      // (64, 8192)

  const size_t WS_NEEDED =
      ((size_t)NNIMG * BSPLIT * KK * CCH + (size_t)NNIMG * BSPLIT * KK) * sizeof(float);

  if (ws_size >= WS_NEEDED) {
    // partial-store path: no atomics, no memset
    float* vp = (float*)d_ws;                             // [1024][8192] f32
    float* agp = vp + (size_t)NNIMG * BSPLIT * KK * CCH;  // [1024][64] f32
    netvlad_main<true><<<NNIMG * BSPLIT, 128, 0, stream>>>(x, conv_w, conv_b, vp, agp);
    netvlad_finish_ws<<<NNIMG * KK / 4, 256, 0, stream>>>(vp, agp, centroids, out);
  } else {
    // atomic fallback
    float* vg = (float*)d_ws;                       // 64*64*128 f32 = 2 MiB
    float* ag = vg + (size_t)NNIMG * KK * CCH;      // 64*64 f32
    const size_t zbytes = ((size_t)NNIMG * KK * CCH + NNIMG * KK) * sizeof(float);
    hipMemsetAsync(d_ws, 0, zbytes, stream);
    netvlad_main<false><<<NNIMG * BSPLIT, 128, 0, stream>>>(x, conv_w, conv_b, vg, ag);
    netvlad_finish<<<NNIMG * KK / 4, 256, 0, stream>>>(vg, ag, centroids, out);
  }
}